// Round 1
// baseline (456.219 us; speedup 1.0000x reference)
//
#include <hip/hip_runtime.h>
#include <math.h>

namespace {
constexpr int kB = 4;
constexpr int kS = 4096;
constexpr int kD = 1024;
constexpr int kM = 128;
constexpr int kC = 128;          // chunk length
constexpr int kNC = kS / kC;     // 32 chunks per batch
constexpr int kRS = kB * kS;     // 16384 rows
constexpr float kDecay = 0.99f;
constexpr float kLR = 0.01f;
}

// ---------------------------------------------------------------------------
// NT GEMM: C[r][n] = sum_k A[r][k] * Bm[n][k] + bias[n]
// 64x64 tile, BK=16, 256 threads, 4x4 per-thread tile. fp32.
// ---------------------------------------------------------------------------
__global__ __launch_bounds__(256)
void gemm_nt_64x64(const float* __restrict__ A, int lda,
                   const float* __restrict__ Bm,
                   const float* __restrict__ bias,
                   float* __restrict__ C, int ldc, int Kdim)
{
  __shared__ __align__(16) float As[16][68];
  __shared__ __align__(16) float Bs[16][68];
  const int t = threadIdx.x;
  const int row0 = blockIdx.x * 64;
  const int n0   = blockIdx.y * 64;
  const int tm = (t >> 4) * 4;   // output rows within tile
  const int tn = (t & 15) * 4;   // output cols within tile
  const int lr = t >> 2;         // load row 0..63
  const int lc = (t & 3) * 4;    // load col 0,4,8,12
  const float* Ap = A  + (size_t)(row0 + lr) * lda  + lc;
  const float* Bp = Bm + (size_t)(n0   + lr) * Kdim + lc;
  float acc[4][4] = {};
  for (int k0 = 0; k0 < Kdim; k0 += 16) {
    float4 av = *(const float4*)(Ap + k0);
    float4 bv = *(const float4*)(Bp + k0);
    __syncthreads();
    As[lc+0][lr] = av.x; As[lc+1][lr] = av.y; As[lc+2][lr] = av.z; As[lc+3][lr] = av.w;
    Bs[lc+0][lr] = bv.x; Bs[lc+1][lr] = bv.y; Bs[lc+2][lr] = bv.z; Bs[lc+3][lr] = bv.w;
    __syncthreads();
#pragma unroll
    for (int k = 0; k < 16; ++k) {
      float4 a4 = *(const float4*)&As[k][tm];
      float4 b4 = *(const float4*)&Bs[k][tn];
      const float am[4] = {a4.x, a4.y, a4.z, a4.w};
      const float bn[4] = {b4.x, b4.y, b4.z, b4.w};
#pragma unroll
      for (int i = 0; i < 4; ++i)
#pragma unroll
        for (int j = 0; j < 4; ++j)
          acc[i][j] = fmaf(am[i], bn[j], acc[i][j]);
    }
  }
#pragma unroll
  for (int i = 0; i < 4; ++i) {
    float4 o;
    o.x = acc[i][0] + bias[n0+tn+0];
    o.y = acc[i][1] + bias[n0+tn+1];
    o.z = acc[i][2] + bias[n0+tn+2];
    o.w = acc[i][3] + bias[n0+tn+3];
    *(float4*)&C[(size_t)(row0+tm+i) * ldc + n0 + tn] = o;
  }
}

// ---------------------------------------------------------------------------
// Per-chunk decayed outer-product sum:
// U[i][j] = LR * sum_{u=0..C-1} d^{C-1-u} * V[u][i] * K[u][j]
// one block per (chunk, batch); 256 threads; 8x8 per-thread tile over (i,j).
// ---------------------------------------------------------------------------
__global__ __launch_bounds__(256)
void chunk_u_kernel(const float* __restrict__ Kb, const float* __restrict__ Vb,
                    float* __restrict__ SU)
{
  __shared__ __align__(16) float Vs[16][128];
  __shared__ __align__(16) float Ks[16][128];
  const int c = blockIdx.x, b = blockIdx.y;
  const float* Kc = Kb + (size_t)(b * kS + c * kC) * kM;
  const float* Vc = Vb + (size_t)(b * kS + c * kC) * kM;
  const int t = threadIdx.x;
  const int ti = (t >> 4) * 8;
  const int tj = (t & 15) * 8;
  const int lu = t >> 4;          // load row 0..15
  const int lx = (t & 15) * 8;    // load col
  float acc[8][8] = {};
  for (int u0 = 0; u0 < kC; u0 += 16) {
    const float w = kLR * powf(kDecay, (float)(kC - 1 - (u0 + lu)));
    float4 v0 = *(const float4*)&Vc[(size_t)(u0+lu)*kM + lx];
    float4 v1 = *(const float4*)&Vc[(size_t)(u0+lu)*kM + lx + 4];
    float4 k0 = *(const float4*)&Kc[(size_t)(u0+lu)*kM + lx];
    float4 k1 = *(const float4*)&Kc[(size_t)(u0+lu)*kM + lx + 4];
    __syncthreads();
    v0.x *= w; v0.y *= w; v0.z *= w; v0.w *= w;
    v1.x *= w; v1.y *= w; v1.z *= w; v1.w *= w;
    *(float4*)&Vs[lu][lx]   = v0;
    *(float4*)&Vs[lu][lx+4] = v1;
    *(float4*)&Ks[lu][lx]   = k0;
    *(float4*)&Ks[lu][lx+4] = k1;
    __syncthreads();
#pragma unroll
    for (int u = 0; u < 16; ++u) {
      float vi[8], kj[8];
      *(float4*)&vi[0] = *(const float4*)&Vs[u][ti];
      *(float4*)&vi[4] = *(const float4*)&Vs[u][ti+4];
      *(float4*)&kj[0] = *(const float4*)&Ks[u][tj];
      *(float4*)&kj[4] = *(const float4*)&Ks[u][tj+4];
#pragma unroll
      for (int i = 0; i < 8; ++i)
#pragma unroll
        for (int j = 0; j < 8; ++j)
          acc[i][j] = fmaf(vi[i], kj[j], acc[i][j]);
    }
  }
  float* Uo = SU + (size_t)(b * kNC + c) * kM * kM;
#pragma unroll
  for (int i = 0; i < 8; ++i) {
    *(float4*)&Uo[(size_t)(ti+i)*kM + tj]     = make_float4(acc[i][0],acc[i][1],acc[i][2],acc[i][3]);
    *(float4*)&Uo[(size_t)(ti+i)*kM + tj + 4] = make_float4(acc[i][4],acc[i][5],acc[i][6],acc[i][7]);
  }
}

// ---------------------------------------------------------------------------
// In-place inter-chunk scan over the U buffer:
//   prev = 0; for c: u = buf[c]; buf[c] = prev (state BEFORE chunk c);
//   prev = d^C * prev + u.  Final prev -> state output.
// One thread per (b, i, j) element.
// ---------------------------------------------------------------------------
__global__ __launch_bounds__(256)
void scan_kernel(float* __restrict__ SU, float* __restrict__ state_out)
{
  const int e  = blockIdx.x * 256 + threadIdx.x;   // < kB*kM*kM
  const int b  = e >> 14;                           // / 16384
  const int ij = e & 16383;
  float* base = SU + (size_t)b * kNC * (kM * kM) + ij;
  const float dC = powf(kDecay, (float)kC);
  float prev = 0.f;
#pragma unroll
  for (int c = 0; c < kNC; ++c) {
    const float u = base[(size_t)c * (kM * kM)];
    base[(size_t)c * (kM * kM)] = prev;
    prev = fmaf(dC, prev, u);
  }
  state_out[e] = prev;
}

// ---------------------------------------------------------------------------
// Per-chunk output:
//   Out[t][i] = sum_{u<t} LR*d^{t-1-u}*(q_t.k_u)*V[u][i]  +  d^t * sum_j Q[t][j]*S[i][j]
// One block per (chunk, batch). Intra-chunk scores staged half at a time
// (u in [0,64) then [64,128)) through LDS to stay under 64 KB LDS.
// ---------------------------------------------------------------------------
__global__ __launch_bounds__(256)
void chunk_out_kernel(const float* __restrict__ Kb, const float* __restrict__ Vb,
                      const float* __restrict__ Qb, const float* __restrict__ SU,
                      float* __restrict__ OutS)
{
  __shared__ __align__(16) float Pbuf[64][132];   // A^T half: Pbuf[u][t]
  __shared__ __align__(16) float Xs[16][128];
  __shared__ __align__(16) float Ys[16][128];
  __shared__ float dpow[kC];
  const int c = blockIdx.x, b = blockIdx.y;
  const int t = threadIdx.x;
  const float* Kc = Kb + (size_t)(b * kS + c * kC) * kM;
  const float* Vc = Vb + (size_t)(b * kS + c * kC) * kM;
  const float* Qc = Qb + (size_t)(b * kS + c * kC) * kM;
  const float* Sc = SU + (size_t)(b * kNC + c) * kM * kM;
  if (t < kC) dpow[t] = powf(kDecay, (float)t);
  const int tr8 = (t >> 4) * 8;   // output rows (local time t)
  const int tc8 = (t & 15) * 8;   // output cols (feature i) / stage-A cols (t)
  const int tu4 = (t >> 4) * 4;   // stage-A rows (u within half)
  const int lrow = t >> 1;        // 128-row transposed loads
  const int lh   = (t & 1) * 8;
  const int lq   = t >> 2;        // 64-row transposed loads
  const int lq4  = (t & 3) * 4;
  const int lv   = t >> 4;        // 16-row direct loads
  const int lx   = (t & 15) * 8;

  float o1[8][8] = {};
#pragma unroll 1
  for (int h = 0; h < 2; ++h) {
    const int ubase = h * 64;
    float pacc[4][8] = {};
    // ---- stage A: P^T[u][t] = sum_j K[u][j] * Q[t][j]  (u in half) ----
#pragma unroll 1
    for (int j0 = 0; j0 < kM; j0 += 16) {
      float4 q0 = *(const float4*)&Qc[(size_t)lrow*kM + j0 + lh];
      float4 q1 = *(const float4*)&Qc[(size_t)lrow*kM + j0 + lh + 4];
      float4 kk = *(const float4*)&Kc[(size_t)(ubase + lq)*kM + j0 + lq4];
      __syncthreads();
      const float qv[8] = {q0.x,q0.y,q0.z,q0.w,q1.x,q1.y,q1.z,q1.w};
#pragma unroll
      for (int i = 0; i < 8; ++i) Xs[lh + i][lrow] = qv[i];
      Ys[lq4+0][lq] = kk.x; Ys[lq4+1][lq] = kk.y;
      Ys[lq4+2][lq] = kk.z; Ys[lq4+3][lq] = kk.w;
      __syncthreads();
#pragma unroll
      for (int j = 0; j < 16; ++j) {
        float ku[4], qt[8];
        *(float4*)&ku[0] = *(const float4*)&Ys[j][tu4];
        *(float4*)&qt[0] = *(const float4*)&Xs[j][tc8];
        *(float4*)&qt[4] = *(const float4*)&Xs[j][tc8 + 4];
#pragma unroll
        for (int iu = 0; iu < 4; ++iu)
#pragma unroll
          for (int jt = 0; jt < 8; ++jt)
            pacc[iu][jt] = fmaf(ku[iu], qt[jt], pacc[iu][jt]);
      }
    }
    // ---- mask + decay, store A^T into Pbuf ----
#pragma unroll
    for (int iu = 0; iu < 4; ++iu) {
      const int u = ubase + tu4 + iu;
      float row[8];
#pragma unroll
      for (int jt = 0; jt < 8; ++jt) {
        const int tl = tc8 + jt;
        row[jt] = (u < tl) ? kLR * dpow[tl - 1 - u] * pacc[iu][jt] : 0.f;
      }
      *(float4*)&Pbuf[tu4 + iu][tc8]     = make_float4(row[0],row[1],row[2],row[3]);
      *(float4*)&Pbuf[tu4 + iu][tc8 + 4] = make_float4(row[4],row[5],row[6],row[7]);
    }
    __syncthreads();
    // ---- stage B1: o1[t][i] += sum_{u in half} A[t][u] * V[u][i] ----
#pragma unroll 1
    for (int u0 = 0; u0 < 64; u0 += 16) {
      float4 v0 = *(const float4*)&Vc[(size_t)(ubase + u0 + lv)*kM + lx];
      float4 v1 = *(const float4*)&Vc[(size_t)(ubase + u0 + lv)*kM + lx + 4];
      __syncthreads();
      *(float4*)&Xs[lv][lx]     = v0;
      *(float4*)&Xs[lv][lx + 4] = v1;
      __syncthreads();
#pragma unroll
      for (int u = 0; u < 16; ++u) {
        float a8[8], v8[8];
        *(float4*)&a8[0] = *(const float4*)&Pbuf[u0 + u][tr8];
        *(float4*)&a8[4] = *(const float4*)&Pbuf[u0 + u][tr8 + 4];
        *(float4*)&v8[0] = *(const float4*)&Xs[u][tc8];
        *(float4*)&v8[4] = *(const float4*)&Xs[u][tc8 + 4];
#pragma unroll
        for (int i = 0; i < 8; ++i)
#pragma unroll
          for (int j = 0; j < 8; ++j)
            o1[i][j] = fmaf(a8[i], v8[j], o1[i][j]);
      }
    }
  }
  // ---- stage B2: o2[t][i] = sum_j Q[t][j] * S[i][j] ----
  float o2[8][8] = {};
#pragma unroll 1
  for (int j0 = 0; j0 < kM; j0 += 16) {
    float4 q0 = *(const float4*)&Qc[(size_t)lrow*kM + j0 + lh];
    float4 q1 = *(const float4*)&Qc[(size_t)lrow*kM + j0 + lh + 4];
    float4 s0 = *(const float4*)&Sc[(size_t)lrow*kM + j0 + lh];
    float4 s1 = *(const float4*)&Sc[(size_t)lrow*kM + j0 + lh + 4];
    __syncthreads();
    const float qv[8] = {q0.x,q0.y,q0.z,q0.w,q1.x,q1.y,q1.z,q1.w};
    const float sv[8] = {s0.x,s0.y,s0.z,s0.w,s1.x,s1.y,s1.z,s1.w};
#pragma unroll
    for (int i = 0; i < 8; ++i) { Xs[lh+i][lrow] = qv[i]; Ys[lh+i][lrow] = sv[i]; }
    __syncthreads();
#pragma unroll
    for (int j = 0; j < 16; ++j) {
      float q8[8], s8[8];
      *(float4*)&q8[0] = *(const float4*)&Xs[j][tr8];
      *(float4*)&q8[4] = *(const float4*)&Xs[j][tr8 + 4];
      *(float4*)&s8[0] = *(const float4*)&Ys[j][tc8];
      *(float4*)&s8[4] = *(const float4*)&Ys[j][tc8 + 4];
#pragma unroll
      for (int i = 0; i < 8; ++i)
#pragma unroll
        for (int j2 = 0; j2 < 8; ++j2)
          o2[i][j2] = fmaf(q8[i], s8[j2], o2[i][j2]);
    }
  }
  // ---- epilogue: Out = o1 + d^t * o2 ----
  float* Oc = OutS + (size_t)(b * kS + c * kC) * kM;
#pragma unroll
  for (int i = 0; i < 8; ++i) {
    const float dt = dpow[tr8 + i];
    float4 w0, w1;
    w0.x = fmaf(dt, o2[i][0], o1[i][0]);
    w0.y = fmaf(dt, o2[i][1], o1[i][1]);
    w0.z = fmaf(dt, o2[i][2], o1[i][2]);
    w0.w = fmaf(dt, o2[i][3], o1[i][3]);
    w1.x = fmaf(dt, o2[i][4], o1[i][4]);
    w1.y = fmaf(dt, o2[i][5], o1[i][5]);
    w1.z = fmaf(dt, o2[i][6], o1[i][6]);
    w1.w = fmaf(dt, o2[i][7], o1[i][7]);
    *(float4*)&Oc[(size_t)(tr8 + i)*kM + tc8]     = w0;
    *(float4*)&Oc[(size_t)(tr8 + i)*kM + tc8 + 4] = w1;
  }
}

// ---------------------------------------------------------------------------
extern "C" void kernel_launch(void* const* d_in, const int* in_sizes, int n_in,
                              void* d_out, int out_size, void* d_ws, size_t ws_size,
                              hipStream_t stream) {
  const float* x  = (const float*)d_in[0];
  const float* Wk = (const float*)d_in[1];
  const float* bk = (const float*)d_in[2];
  const float* Wv = (const float*)d_in[3];
  const float* bv = (const float*)d_in[4];
  const float* Wq = (const float*)d_in[5];
  const float* bq = (const float*)d_in[6];
  const float* Wo = (const float*)d_in[7];
  const float* bo = (const float*)d_in[8];

  float* ws = (float*)d_ws;
  const size_t PROJ = (size_t)kRS * kM;   // 2,097,152 floats
  float* Kb   = ws;
  float* Vb   = ws + PROJ;
  float* Qb   = ws + 2 * PROJ;
  float* OutS = ws + 3 * PROJ;
  float* SU   = ws + 4 * PROJ;            // kB*kNC*kM*kM = 2,097,152 floats

  float* y = (float*)d_out;
  float* state_out = y + (size_t)kRS * kD;

  dim3 blk(256);
  // projections: K/V/Q = x @ W^T + b
  gemm_nt_64x64<<<dim3(kRS/64, kM/64), blk, 0, stream>>>(x, kD, Wk, bk, Kb, kM, kD);
  gemm_nt_64x64<<<dim3(kRS/64, kM/64), blk, 0, stream>>>(x, kD, Wv, bv, Vb, kM, kD);
  gemm_nt_64x64<<<dim3(kRS/64, kM/64), blk, 0, stream>>>(x, kD, Wq, bq, Qb, kM, kD);
  // per-chunk decayed outer-product sums
  chunk_u_kernel<<<dim3(kNC, kB), blk, 0, stream>>>(Kb, Vb, SU);
  // inter-chunk state scan (in place) + final state output
  scan_kernel<<<dim3(kB*kM*kM/256), blk, 0, stream>>>(SU, state_out);
  // per-chunk outputs
  chunk_out_kernel<<<dim3(kNC, kB), blk, 0, stream>>>(Kb, Vb, Qb, SU, OutS);
  // y = Out @ Wo^T + bo
  gemm_nt_64x64<<<dim3(kRS/64, kD/64), blk, 0, stream>>>(OutS, kM, Wo, bo, y, kD, kM);
}

// Round 2
// 253.416 us; speedup vs baseline: 1.8003x; 1.8003x over previous
//
#include <hip/hip_runtime.h>
#include <math.h>

namespace {
constexpr int kB = 4;
constexpr int kS = 4096;
constexpr int kD = 1024;
constexpr int kM = 128;
constexpr int kC = 128;          // chunk length
constexpr int kNC = kS / kC;     // 32 chunks per batch
constexpr int kRS = kB * kS;     // 16384 rows
constexpr float kDecay = 0.99f;
constexpr float kLR = 0.01f;
}

typedef __bf16 bf16x8 __attribute__((ext_vector_type(8)));
typedef float  f32x4  __attribute__((ext_vector_type(4)));
typedef unsigned short u16;
typedef unsigned int   u32;

__device__ __forceinline__ u16 f2bf(float f) {
  u32 x = __float_as_uint(f);
  u32 r = (x + 0x7fffu + ((x >> 16) & 1u)) >> 16;   // RNE
  return (u16)r;
}

__device__ __forceinline__ void gl_lds16(const void* g, void* l) {
  __builtin_amdgcn_global_load_lds(
      (const __attribute__((address_space(1))) void*)g,
      (__attribute__((address_space(3))) void*)l, 16, 0, 0);
}

// ---------------------------------------------------------------------------
// cast x (fp32) -> bf16, 4 elems/thread
// ---------------------------------------------------------------------------
__global__ __launch_bounds__(256)
void cast_x_kernel(const float* __restrict__ x, u16* __restrict__ xh, int n)
{
  int i = (blockIdx.x * 256 + threadIdx.x) * 4;
  if (i >= n) return;
  float4 v = *(const float4*)&x[i];
  ushort4 o;
  o.x = f2bf(v.x); o.y = f2bf(v.y); o.z = f2bf(v.z); o.w = f2bf(v.w);
  *(ushort4*)&xh[i] = o;
}

// cast Wk|Wv|Wq (concat -> Wkvq[384][1024]) and Wo -> Woh[1024][128]
__global__ __launch_bounds__(256)
void cast_w_kernel(const float* __restrict__ Wk, const float* __restrict__ Wv,
                   const float* __restrict__ Wq, const float* __restrict__ Wo,
                   u16* __restrict__ Wkvq, u16* __restrict__ Woh)
{
  int i = (blockIdx.x * 256 + threadIdx.x) * 4;   // < 524288
  const float* src;
  u16* dst;
  if (i < 393216) {
    src = (i < 131072) ? Wk + i : (i < 262144) ? Wv + (i - 131072) : Wq + (i - 262144);
    dst = Wkvq + i;
  } else {
    src = Wo + (i - 393216);
    dst = Woh + (i - 393216);
  }
  float4 v = *(const float4*)src;
  ushort4 o;
  o.x = f2bf(v.x); o.y = f2bf(v.y); o.z = f2bf(v.z); o.w = f2bf(v.w);
  *(ushort4*)dst = o;
}

// ---------------------------------------------------------------------------
// bf16 MFMA NT GEMM: C[r][n] = sum_k A[r][k]*Bm[n][k] + bias[n]
// 128x128 tile, BK=32, 256 threads (4 waves), each wave 64x64 via 4x4
// mfma_f32_16x16x32_bf16. global_load_lds width-16 staging (m97 structure).
// split==1: blockIdx.y selects {c0,b0}/{c1,b1}/{c2,b2}, each ld ldc.
// ---------------------------------------------------------------------------
__global__ __launch_bounds__(256, 2)
void gemm_nt_bf16(const u16* __restrict__ A, int lda,
                  const u16* __restrict__ Bm, int Kdim,
                  const float* __restrict__ b0, const float* __restrict__ b1,
                  const float* __restrict__ b2,
                  float* __restrict__ c0, float* __restrict__ c1,
                  float* __restrict__ c2, int ldc, int split)
{
  __shared__ __align__(16) u16 As[128 * 32];
  __shared__ __align__(16) u16 Bs[128 * 32];
  const int tid  = threadIdx.x;
  const int wave = tid >> 6;
  const int lane = tid & 63;
  const int row0 = blockIdx.x * 128;
  const int n0   = blockIdx.y * 128;

  const float* bias; float* dst; int colBase;
  if (split) {
    const int w = blockIdx.y;
    bias = (w == 0) ? b0 : (w == 1) ? b1 : b2;
    dst  = (w == 0) ? c0 : (w == 1) ? c1 : c2;
    colBase = 0;
  } else {
    bias = b0; dst = c0; colBase = n0;
  }

  const int mW = (wave >> 1) * 64;
  const int nW = (wave & 1) * 64;
  // staging coordinates
  const int srow = wave * 32 + (lane >> 2);      // +16 for second instr
  const int skc  = (lane & 3) * 8;
  const u16* gA0 = A  + (size_t)(row0 + srow) * lda  + skc;
  const u16* gA1 = A  + (size_t)(row0 + srow + 16) * lda + skc;
  const u16* gB0 = Bm + (size_t)(n0 + srow) * Kdim + skc;
  const u16* gB1 = Bm + (size_t)(n0 + srow + 16) * Kdim + skc;
  u16* lA0 = &As[(wave * 32) * 32];
  u16* lA1 = &As[(wave * 32 + 16) * 32];
  u16* lB0 = &Bs[(wave * 32) * 32];
  u16* lB1 = &Bs[(wave * 32 + 16) * 32];
  // fragment coordinates
  const int fr = lane & 15;
  const int fk = (lane >> 4) * 8;

  f32x4 acc[4][4] = {};

  for (int k0 = 0; k0 < Kdim; k0 += 32) {
    __syncthreads();
    gl_lds16(gA0 + k0, lA0);
    gl_lds16(gA1 + k0, lA1);
    gl_lds16(gB0 + k0, lB0);
    gl_lds16(gB1 + k0, lB1);
    __syncthreads();
    bf16x8 av[4], bv[4];
#pragma unroll
    for (int mi = 0; mi < 4; ++mi)
      av[mi] = *(const bf16x8*)&As[(mW + mi * 16 + fr) * 32 + fk];
#pragma unroll
    for (int ni = 0; ni < 4; ++ni)
      bv[ni] = *(const bf16x8*)&Bs[(nW + ni * 16 + fr) * 32 + fk];
#pragma unroll
    for (int mi = 0; mi < 4; ++mi)
#pragma unroll
      for (int ni = 0; ni < 4; ++ni)
        acc[mi][ni] = __builtin_amdgcn_mfma_f32_16x16x32_bf16(av[mi], bv[ni], acc[mi][ni], 0, 0, 0);
  }

  // epilogue: D[row=(lane>>4)*4+r][col=lane&15]
  const int orow = (lane >> 4) * 4;
#pragma unroll
  for (int mi = 0; mi < 4; ++mi) {
#pragma unroll
    for (int ni = 0; ni < 4; ++ni) {
      const int cn = colBase + nW + ni * 16 + fr;
      const float bb = bias[cn];
#pragma unroll
      for (int r = 0; r < 4; ++r) {
        const int gm = row0 + mW + mi * 16 + orow + r;
        dst[(size_t)gm * ldc + cn] = acc[mi][ni][r] + bb;
      }
    }
  }
}

// ---------------------------------------------------------------------------
// Per-chunk decayed outer-product sum (fp32):
// U[i][j] = LR * sum_u d^{C-1-u} * V[u][i] * K[u][j]
// ---------------------------------------------------------------------------
__global__ __launch_bounds__(256)
void chunk_u_kernel(const float* __restrict__ Kb, const float* __restrict__ Vb,
                    float* __restrict__ SU)
{
  __shared__ __align__(16) float Vs[16][128];
  __shared__ __align__(16) float Ks[16][128];
  const int c = blockIdx.x, b = blockIdx.y;
  const float* Kc = Kb + (size_t)(b * kS + c * kC) * kM;
  const float* Vc = Vb + (size_t)(b * kS + c * kC) * kM;
  const int t = threadIdx.x;
  const int ti = (t >> 4) * 8;
  const int tj = (t & 15) * 8;
  const int lu = t >> 4;
  const int lx = (t & 15) * 8;
  float acc[8][8] = {};
  for (int u0 = 0; u0 < kC; u0 += 16) {
    const float w = kLR * powf(kDecay, (float)(kC - 1 - (u0 + lu)));
    float4 v0 = *(const float4*)&Vc[(size_t)(u0+lu)*kM + lx];
    float4 v1 = *(const float4*)&Vc[(size_t)(u0+lu)*kM + lx + 4];
    float4 k0 = *(const float4*)&Kc[(size_t)(u0+lu)*kM + lx];
    float4 k1 = *(const float4*)&Kc[(size_t)(u0+lu)*kM + lx + 4];
    __syncthreads();
    v0.x *= w; v0.y *= w; v0.z *= w; v0.w *= w;
    v1.x *= w; v1.y *= w; v1.z *= w; v1.w *= w;
    *(float4*)&Vs[lu][lx]   = v0;
    *(float4*)&Vs[lu][lx+4] = v1;
    *(float4*)&Ks[lu][lx]   = k0;
    *(float4*)&Ks[lu][lx+4] = k1;
    __syncthreads();
#pragma unroll
    for (int u = 0; u < 16; ++u) {
      float vi[8], kj[8];
      *(float4*)&vi[0] = *(const float4*)&Vs[u][ti];
      *(float4*)&vi[4] = *(const float4*)&Vs[u][ti+4];
      *(float4*)&kj[0] = *(const float4*)&Ks[u][tj];
      *(float4*)&kj[4] = *(const float4*)&Ks[u][tj+4];
#pragma unroll
      for (int i = 0; i < 8; ++i)
#pragma unroll
        for (int j = 0; j < 8; ++j)
          acc[i][j] = fmaf(vi[i], kj[j], acc[i][j]);
    }
  }
  float* Uo = SU + (size_t)(b * kNC + c) * kM * kM;
#pragma unroll
  for (int i = 0; i < 8; ++i) {
    *(float4*)&Uo[(size_t)(ti+i)*kM + tj]     = make_float4(acc[i][0],acc[i][1],acc[i][2],acc[i][3]);
    *(float4*)&Uo[(size_t)(ti+i)*kM + tj + 4] = make_float4(acc[i][4],acc[i][5],acc[i][6],acc[i][7]);
  }
}

// ---------------------------------------------------------------------------
// In-place inter-chunk scan; final carry -> state output.
// ---------------------------------------------------------------------------
__global__ __launch_bounds__(256)
void scan_kernel(float* __restrict__ SU, float* __restrict__ state_out)
{
  const int e  = blockIdx.x * 256 + threadIdx.x;
  const int b  = e >> 14;
  const int ij = e & 16383;
  float* base = SU + (size_t)b * kNC * (kM * kM) + ij;
  const float dC = powf(kDecay, (float)kC);
  float prev = 0.f;
#pragma unroll
  for (int c = 0; c < kNC; ++c) {
    const float u = base[(size_t)c * (kM * kM)];
    base[(size_t)c * (kM * kM)] = prev;
    prev = fmaf(dC, prev, u);
  }
  state_out[e] = prev;
}

// ---------------------------------------------------------------------------
// Per-chunk output (fp32 compute), writes OutS as bf16:
//   Out[t][i] = sum_{u<t} LR*d^{t-1-u}*(q_t.k_u)*V[u][i] + d^t*sum_j Q[t][j]*S[i][j]
// ---------------------------------------------------------------------------
__global__ __launch_bounds__(256)
void chunk_out_kernel(const float* __restrict__ Kb, const float* __restrict__ Vb,
                      const float* __restrict__ Qb, const float* __restrict__ SU,
                      u16* __restrict__ OutS)
{
  __shared__ __align__(16) float Pbuf[64][132];
  __shared__ __align__(16) float Xs[16][128];
  __shared__ __align__(16) float Ys[16][128];
  __shared__ float dpow[kC];
  const int c = blockIdx.x, b = blockIdx.y;
  const int t = threadIdx.x;
  const float* Kc = Kb + (size_t)(b * kS + c * kC) * kM;
  const float* Vc = Vb + (size_t)(b * kS + c * kC) * kM;
  const float* Qc = Qb + (size_t)(b * kS + c * kC) * kM;
  const float* Sc = SU + (size_t)(b * kNC + c) * kM * kM;
  if (t < kC) dpow[t] = powf(kDecay, (float)t);
  const int tr8 = (t >> 4) * 8;
  const int tc8 = (t & 15) * 8;
  const int tu4 = (t >> 4) * 4;
  const int lrow = t >> 1;
  const int lh   = (t & 1) * 8;
  const int lq   = t >> 2;
  const int lq4  = (t & 3) * 4;
  const int lv   = t >> 4;
  const int lx   = (t & 15) * 8;

  float o1[8][8] = {};
#pragma unroll 1
  for (int h = 0; h < 2; ++h) {
    const int ubase = h * 64;
    float pacc[4][8] = {};
#pragma unroll 1
    for (int j0 = 0; j0 < kM; j0 += 16) {
      float4 q0 = *(const float4*)&Qc[(size_t)lrow*kM + j0 + lh];
      float4 q1 = *(const float4*)&Qc[(size_t)lrow*kM + j0 + lh + 4];
      float4 kk = *(const float4*)&Kc[(size_t)(ubase + lq)*kM + j0 + lq4];
      __syncthreads();
      const float qv[8] = {q0.x,q0.y,q0.z,q0.w,q1.x,q1.y,q1.z,q1.w};
#pragma unroll
      for (int i = 0; i < 8; ++i) Xs[lh + i][lrow] = qv[i];
      Ys[lq4+0][lq] = kk.x; Ys[lq4+1][lq] = kk.y;
      Ys[lq4+2][lq] = kk.z; Ys[lq4+3][lq] = kk.w;
      __syncthreads();
#pragma unroll
      for (int j = 0; j < 16; ++j) {
        float ku[4], qt[8];
        *(float4*)&ku[0] = *(const float4*)&Ys[j][tu4];
        *(float4*)&qt[0] = *(const float4*)&Xs[j][tc8];
        *(float4*)&qt[4] = *(const float4*)&Xs[j][tc8 + 4];
#pragma unroll
        for (int iu = 0; iu < 4; ++iu)
#pragma unroll
          for (int jt = 0; jt < 8; ++jt)
            pacc[iu][jt] = fmaf(ku[iu], qt[jt], pacc[iu][jt]);
      }
    }
#pragma unroll
    for (int iu = 0; iu < 4; ++iu) {
      const int u = ubase + tu4 + iu;
      float row[8];
#pragma unroll
      for (int jt = 0; jt < 8; ++jt) {
        const int tl = tc8 + jt;
        row[jt] = (u < tl) ? kLR * dpow[tl - 1 - u] * pacc[iu][jt] : 0.f;
      }
      *(float4*)&Pbuf[tu4 + iu][tc8]     = make_float4(row[0],row[1],row[2],row[3]);
      *(float4*)&Pbuf[tu4 + iu][tc8 + 4] = make_float4(row[4],row[5],row[6],row[7]);
    }
    __syncthreads();
#pragma unroll 1
    for (int u0 = 0; u0 < 64; u0 += 16) {
      float4 v0 = *(const float4*)&Vc[(size_t)(ubase + u0 + lv)*kM + lx];
      float4 v1 = *(const float4*)&Vc[(size_t)(ubase + u0 + lv)*kM + lx + 4];
      __syncthreads();
      *(float4*)&Xs[lv][lx]     = v0;
      *(float4*)&Xs[lv][lx + 4] = v1;
      __syncthreads();
#pragma unroll
      for (int u = 0; u < 16; ++u) {
        float a8[8], v8[8];
        *(float4*)&a8[0] = *(const float4*)&Pbuf[u0 + u][tr8];
        *(float4*)&a8[4] = *(const float4*)&Pbuf[u0 + u][tr8 + 4];
        *(float4*)&v8[0] = *(const float4*)&Xs[u][tc8];
        *(float4*)&v8[4] = *(const float4*)&Xs[u][tc8 + 4];
#pragma unroll
        for (int i = 0; i < 8; ++i)
#pragma unroll
          for (int j = 0; j < 8; ++j)
            o1[i][j] = fmaf(a8[i], v8[j], o1[i][j]);
      }
    }
  }
  float o2[8][8] = {};
#pragma unroll 1
  for (int j0 = 0; j0 < kM; j0 += 16) {
    float4 q0 = *(const float4*)&Qc[(size_t)lrow*kM + j0 + lh];
    float4 q1 = *(const float4*)&Qc[(size_t)lrow*kM + j0 + lh + 4];
    float4 s0 = *(const float4*)&Sc[(size_t)lrow*kM + j0 + lh];
    float4 s1 = *(const float4*)&Sc[(size_t)lrow*kM + j0 + lh + 4];
    __syncthreads();
    const float qv[8] = {q0.x,q0.y,q0.z,q0.w,q1.x,q1.y,q1.z,q1.w};
    const float sv[8] = {s0.x,s0.y,s0.z,s0.w,s1.x,s1.y,s1.z,s1.w};
#pragma unroll
    for (int i = 0; i < 8; ++i) { Xs[lh+i][lrow] = qv[i]; Ys[lh+i][lrow] = sv[i]; }
    __syncthreads();
#pragma unroll
    for (int j = 0; j < 16; ++j) {
      float q8[8], s8[8];
      *(float4*)&q8[0] = *(const float4*)&Xs[j][tr8];
      *(float4*)&q8[4] = *(const float4*)&Xs[j][tr8 + 4];
      *(float4*)&s8[0] = *(const float4*)&Ys[j][tc8];
      *(float4*)&s8[4] = *(const float4*)&Ys[j][tc8 + 4];
#pragma unroll
      for (int i = 0; i < 8; ++i)
#pragma unroll
        for (int j2 = 0; j2 < 8; ++j2)
          o2[i][j2] = fmaf(q8[i], s8[j2], o2[i][j2]);
    }
  }
  u16* Oc = OutS + (size_t)(b * kS + c * kC) * kM;
#pragma unroll
  for (int i = 0; i < 8; ++i) {
    const float dt = dpow[tr8 + i];
    u16 h[8];
#pragma unroll
    for (int j = 0; j < 8; ++j)
      h[j] = f2bf(fmaf(dt, o2[i][j], o1[i][j]));
    uint4 pk;
    pk.x = (u32)h[0] | ((u32)h[1] << 16);
    pk.y = (u32)h[2] | ((u32)h[3] << 16);
    pk.z = (u32)h[4] | ((u32)h[5] << 16);
    pk.w = (u32)h[6] | ((u32)h[7] << 16);
    *(uint4*)&Oc[(size_t)(tr8 + i)*kM + tc8] = pk;
  }
}

// ---------------------------------------------------------------------------
extern "C" void kernel_launch(void* const* d_in, const int* in_sizes, int n_in,
                              void* d_out, int out_size, void* d_ws, size_t ws_size,
                              hipStream_t stream) {
  const float* x  = (const float*)d_in[0];
  const float* Wk = (const float*)d_in[1];
  const float* bk = (const float*)d_in[2];
  const float* Wv = (const float*)d_in[3];
  const float* bv = (const float*)d_in[4];
  const float* Wq = (const float*)d_in[5];
  const float* bq = (const float*)d_in[6];
  const float* Wo = (const float*)d_in[7];
  const float* bo = (const float*)d_in[8];

  char* w = (char*)d_ws;
  const size_t PROJ_B = (size_t)kRS * kM * 4;      // 8 MB
  float* Kb   = (float*)w;                 w += PROJ_B;
  float* Vb   = (float*)w;                 w += PROJ_B;
  float* Qb   = (float*)w;                 w += PROJ_B;
  float* SU   = (float*)w;                 w += PROJ_B;            // kB*kNC*kM*kM fp32
  u16*   OutS = (u16*)w;                   w += (size_t)kRS * kM * 2;
  u16*   xh   = (u16*)w;                   w += (size_t)kRS * kD * 2;
  u16*   Wkvq = (u16*)w;                   w += (size_t)384 * kD * 2;
  u16*   Woh  = (u16*)w;                   w += (size_t)kD * kM * 2;

  float* y = (float*)d_out;
  float* state_out = y + (size_t)kRS * kD;

  dim3 blk(256);
  // bf16 casts
  cast_x_kernel<<<dim3(kRS * kD / 4 / 256), blk, 0, stream>>>(x, xh, kRS * kD);
  cast_w_kernel<<<dim3(524288 / 4 / 256), blk, 0, stream>>>(Wk, Wv, Wq, Wo, Wkvq, Woh);
  // fused K/V/Q projection: [16384x1024] @ [384x1024]^T -> split fp32 K/V/Q
  gemm_nt_bf16<<<dim3(kRS / 128, 3), blk, 0, stream>>>(
      xh, kD, Wkvq, kD, bk, bv, bq, Kb, Vb, Qb, kM, 1);
  // per-chunk decayed outer-product sums
  chunk_u_kernel<<<dim3(kNC, kB), blk, 0, stream>>>(Kb, Vb, SU);
  // inter-chunk state scan + final state output
  scan_kernel<<<dim3(kB*kM*kM/256), blk, 0, stream>>>(SU, state_out);
  // per-chunk outputs (bf16 OutS)
  chunk_out_kernel<<<dim3(kNC, kB), blk, 0, stream>>>(Kb, Vb, Qb, SU, OutS);
  // y = OutS @ Wo^T + bo : [16384x128] @ [1024x128]^T
  gemm_nt_bf16<<<dim3(kRS / 128, kD / 128), blk, 0, stream>>>(
      OutS, kM, Woh, kM, bo, nullptr, nullptr, y, nullptr, nullptr, kD, 0);
}

// Round 3
// 209.941 us; speedup vs baseline: 2.1731x; 1.2071x over previous
//
#include <hip/hip_runtime.h>
#include <math.h>

namespace {
constexpr int kB = 4;
constexpr int kS = 4096;
constexpr int kD = 1024;
constexpr int kM = 128;
constexpr int kC = 128;          // chunk length
constexpr int kNC = kS / kC;     // 32 chunks per batch
constexpr int kRS = kB * kS;     // 16384 rows
constexpr float kLR = 0.01f;
constexpr float kLog2d = -0.0144995696f;   // log2(0.99)
}

typedef __bf16 bf16x8 __attribute__((ext_vector_type(8)));
typedef float  f32x4  __attribute__((ext_vector_type(4)));
typedef unsigned short u16;
typedef unsigned int   u32;

__device__ __forceinline__ u16 f2bf(float f) {
  u32 x = __float_as_uint(f);
  u32 r = (x + 0x7fffu + ((x >> 16) & 1u)) >> 16;   // RNE
  return (u16)r;
}

__device__ __forceinline__ float bf2f(u16 h) {
  return __uint_as_float(((u32)h) << 16);
}

__device__ __forceinline__ void gl_lds16(const void* g, void* l) {
  __builtin_amdgcn_global_load_lds(
      (const __attribute__((address_space(1))) void*)g,
      (__attribute__((address_space(3))) void*)l, 16, 0, 0);
}

__device__ __forceinline__ f32x4 mf(bf16x8 a, bf16x8 b, f32x4 c) {
  return __builtin_amdgcn_mfma_f32_16x16x32_bf16(a, b, c, 0, 0, 0);
}

// ---------------------------------------------------------------------------
// cast x (fp32) -> bf16
// ---------------------------------------------------------------------------
__global__ __launch_bounds__(256)
void cast_x_kernel(const float* __restrict__ x, u16* __restrict__ xh, int n)
{
  int i = (blockIdx.x * 256 + threadIdx.x) * 4;
  if (i >= n) return;
  float4 v = *(const float4*)&x[i];
  ushort4 o;
  o.x = f2bf(v.x); o.y = f2bf(v.y); o.z = f2bf(v.z); o.w = f2bf(v.w);
  *(ushort4*)&xh[i] = o;
}

// cast Wk|Wv|Wq (concat -> Wkvq[384][1024]) and Wo -> Woh[1024][128]
__global__ __launch_bounds__(256)
void cast_w_kernel(const float* __restrict__ Wk, const float* __restrict__ Wv,
                   const float* __restrict__ Wq, const float* __restrict__ Wo,
                   u16* __restrict__ Wkvq, u16* __restrict__ Woh)
{
  int i = (blockIdx.x * 256 + threadIdx.x) * 4;   // < 524288
  const float* src;
  u16* dst;
  if (i < 393216) {
    src = (i < 131072) ? Wk + i : (i < 262144) ? Wv + (i - 131072) : Wq + (i - 262144);
    dst = Wkvq + i;
  } else {
    src = Wo + (i - 393216);
    dst = Woh + (i - 393216);
  }
  float4 v = *(const float4*)src;
  ushort4 o;
  o.x = f2bf(v.x); o.y = f2bf(v.y); o.z = f2bf(v.z); o.w = f2bf(v.w);
  *(ushort4*)dst = o;
}

// ---------------------------------------------------------------------------
// Projection GEMM (bf16 in, bf16 out): C = A @ Bm^T + bias
// A [16384][1024], Bm = Wkvq [384][1024]; blockIdx.y selects k/v/q slab.
// 128x128 tile, BK=32, m97 structure.
// ---------------------------------------------------------------------------
__global__ __launch_bounds__(256, 2)
void gemm_proj(const u16* __restrict__ A, const u16* __restrict__ Bm,
               const float* __restrict__ b0, const float* __restrict__ b1,
               const float* __restrict__ b2,
               u16* __restrict__ c0, u16* __restrict__ c1, u16* __restrict__ c2)
{
  __shared__ __align__(16) u16 As[128 * 32];
  __shared__ __align__(16) u16 Bs[128 * 32];
  const int tid = threadIdx.x, wave = tid >> 6, lane = tid & 63;
  const int row0 = blockIdx.x * 128;
  const int wsel = blockIdx.y;
  const float* bias = (wsel == 0) ? b0 : (wsel == 1) ? b1 : b2;
  u16* dst = (wsel == 0) ? c0 : (wsel == 1) ? c1 : c2;

  const int mW = (wave >> 1) * 64, nW = (wave & 1) * 64;
  const int srow = wave * 32 + (lane >> 2);
  const int skc  = (lane & 3) * 8;
  const u16* gA0 = A  + (size_t)(row0 + srow) * kD + skc;
  const u16* gA1 = gA0 + (size_t)16 * kD;
  const u16* gB0 = Bm + (size_t)(wsel * 128 + srow) * kD + skc;
  const u16* gB1 = gB0 + (size_t)16 * kD;
  u16* lA0 = &As[(wave * 32) * 32];
  u16* lA1 = &As[(wave * 32 + 16) * 32];
  u16* lB0 = &Bs[(wave * 32) * 32];
  u16* lB1 = &Bs[(wave * 32 + 16) * 32];
  const int fr = lane & 15, fk = (lane >> 4) * 8;

  f32x4 acc[4][4] = {};
  for (int k0 = 0; k0 < kD; k0 += 32) {
    __syncthreads();
    gl_lds16(gA0 + k0, lA0);
    gl_lds16(gA1 + k0, lA1);
    gl_lds16(gB0 + k0, lB0);
    gl_lds16(gB1 + k0, lB1);
    __syncthreads();
    bf16x8 av[4], bv[4];
#pragma unroll
    for (int mi = 0; mi < 4; ++mi) av[mi] = *(const bf16x8*)&As[(mW + mi * 16 + fr) * 32 + fk];
#pragma unroll
    for (int ni = 0; ni < 4; ++ni) bv[ni] = *(const bf16x8*)&Bs[(nW + ni * 16 + fr) * 32 + fk];
#pragma unroll
    for (int mi = 0; mi < 4; ++mi)
#pragma unroll
      for (int ni = 0; ni < 4; ++ni)
        acc[mi][ni] = mf(av[mi], bv[ni], acc[mi][ni]);
  }
  const int orow = (lane >> 4) * 4;
#pragma unroll
  for (int mi = 0; mi < 4; ++mi)
#pragma unroll
    for (int ni = 0; ni < 4; ++ni) {
      const int cn = nW + ni * 16 + fr;
      const float bb = bias[cn];
#pragma unroll
      for (int r = 0; r < 4; ++r)
        dst[(size_t)(row0 + mW + mi * 16 + orow + r) * kM + cn] = f2bf(acc[mi][ni][r] + bb);
    }
}

// ---------------------------------------------------------------------------
// Output GEMM (bf16 in, fp32 out): y = OutS @ Woh^T + bo, K=128
// ---------------------------------------------------------------------------
__global__ __launch_bounds__(256, 2)
void gemm_final(const u16* __restrict__ A, const u16* __restrict__ Bm,
                const float* __restrict__ bias, float* __restrict__ dst)
{
  __shared__ __align__(16) u16 As[128 * 32];
  __shared__ __align__(16) u16 Bs[128 * 32];
  const int tid = threadIdx.x, wave = tid >> 6, lane = tid & 63;
  const int row0 = blockIdx.x * 128;
  const int n0   = blockIdx.y * 128;
  const int mW = (wave >> 1) * 64, nW = (wave & 1) * 64;
  const int srow = wave * 32 + (lane >> 2);
  const int skc  = (lane & 3) * 8;
  const u16* gA0 = A  + (size_t)(row0 + srow) * kM + skc;
  const u16* gA1 = gA0 + (size_t)16 * kM;
  const u16* gB0 = Bm + (size_t)(n0 + srow) * kM + skc;
  const u16* gB1 = gB0 + (size_t)16 * kM;
  u16* lA0 = &As[(wave * 32) * 32];
  u16* lA1 = &As[(wave * 32 + 16) * 32];
  u16* lB0 = &Bs[(wave * 32) * 32];
  u16* lB1 = &Bs[(wave * 32 + 16) * 32];
  const int fr = lane & 15, fk = (lane >> 4) * 8;

  f32x4 acc[4][4] = {};
  for (int k0 = 0; k0 < kM; k0 += 32) {
    __syncthreads();
    gl_lds16(gA0 + k0, lA0);
    gl_lds16(gA1 + k0, lA1);
    gl_lds16(gB0 + k0, lB0);
    gl_lds16(gB1 + k0, lB1);
    __syncthreads();
    bf16x8 av[4], bv[4];
#pragma unroll
    for (int mi = 0; mi < 4; ++mi) av[mi] = *(const bf16x8*)&As[(mW + mi * 16 + fr) * 32 + fk];
#pragma unroll
    for (int ni = 0; ni < 4; ++ni) bv[ni] = *(const bf16x8*)&Bs[(nW + ni * 16 + fr) * 32 + fk];
#pragma unroll
    for (int mi = 0; mi < 4; ++mi)
#pragma unroll
      for (int ni = 0; ni < 4; ++ni)
        acc[mi][ni] = mf(av[mi], bv[ni], acc[mi][ni]);
  }
  const int orow = (lane >> 4) * 4;
#pragma unroll
  for (int mi = 0; mi < 4; ++mi)
#pragma unroll
    for (int ni = 0; ni < 4; ++ni) {
      const int cn = n0 + nW + ni * 16 + fr;
      const float bb = bias[cn];
#pragma unroll
      for (int r = 0; r < 4; ++r)
        dst[(size_t)(row0 + mW + mi * 16 + orow + r) * kD + cn] = acc[mi][ni][r] + bb;
    }
}

// ---------------------------------------------------------------------------
// Transpose K,V per chunk: Kwt[j][u] = LR*d^{127-u}*K[u][j], Vt[i][u] = V[u][i]
// grid (kNC, kB, 2): z=0 -> K->Kwt (scaled), z=1 -> V->Vt.
// ---------------------------------------------------------------------------
__global__ __launch_bounds__(256)
void transpose_kv_kernel(const u16* __restrict__ Kb16, const u16* __restrict__ Vb16,
                         u16* __restrict__ Kwt, u16* __restrict__ Vt)
{
  __shared__ __align__(16) u16 T[128 * 136];
  const int c = blockIdx.x, b = blockIdx.y, z = blockIdx.z;
  const size_t cb = (size_t)(b * kNC + c) * 16384;
  const u16* src = (z ? Vb16 : Kb16) + cb;
  u16* dst = (z ? Vt : Kwt) + cb;
  const int t = threadIdx.x;
  {
    const int r = t >> 4, c8 = (t & 15) * 8;
#pragma unroll
    for (int i = 0; i < 8; ++i) {
      uint4 v = *(const uint4*)&src[(size_t)(r + i * 16) * kM + c8];
      *(uint4*)&T[(r + i * 16) * 136 + c8] = v;
    }
  }
  __syncthreads();
  const int j = t >> 1, u0 = (t & 1) * 64;
  const bool scale = (z == 0);
#pragma unroll 1
  for (int s8 = 0; s8 < 8; ++s8) {
    u16 outv[8];
#pragma unroll
    for (int k = 0; k < 8; ++k) {
      const int u = u0 + s8 * 8 + k;
      u16 raw = T[u * 136 + j];
      if (scale) {
        float f = bf2f(raw) * (kLR * exp2f((float)(127 - u) * kLog2d));
        raw = f2bf(f);
      }
      outv[k] = raw;
    }
    *(uint4*)&dst[(size_t)j * kM + u0 + s8 * 8] = *(uint4*)outv;
  }
}

// ---------------------------------------------------------------------------
// chunk_intra: per (chunk,batch):
//   P = Q K^T (MFMA) -> mask/decay -> At (bf16, LDS)
//   O1 = At * V   (A=At, B=Vt)
//   U  = Vw^T K   (A=Vt, B=Kwt)   [Vt fragments shared with O1]
// LDS: R1 = Q panels -> At panels; R2 = K panels -> {Vt half | Kwt half}.
// ---------------------------------------------------------------------------
__global__ __launch_bounds__(256)
void chunk_intra_kernel(const u16* __restrict__ Qg, const u16* __restrict__ Kg,
                        const u16* __restrict__ VtG, const u16* __restrict__ KwtG,
                        float* __restrict__ O1, float* __restrict__ SU)
{
  __shared__ __align__(16) u16 R1[16384];
  __shared__ __align__(16) u16 R2[16384];
  const int c = blockIdx.x, b = blockIdx.y;
  const size_t cb = (size_t)(b * kNC + c) * 16384;
  const int tid = threadIdx.x, wave = tid >> 6, lane = tid & 63;
  const int fr = lane & 15, qd = lane >> 4;
  const int mW = (wave >> 1) * 64, nW = (wave & 1) * 64;

  // stage Q->R1, K->R2 as 4 panels of [128][32] (panel p = k in [32p, 32p+32))
  {
    const size_t go = cb + (size_t)(lane >> 2) * kM + wave * 32 + (lane & 3) * 8;
    u16* l1 = R1 + wave * 4096;
    u16* l2 = R2 + wave * 4096;
#pragma unroll
    for (int i = 0; i < 8; ++i) {
      gl_lds16(Qg + go + (size_t)i * 16 * kM, l1 + i * 512);
      gl_lds16(Kg + go + (size_t)i * 16 * kM, l2 + i * 512);
    }
  }
  __syncthreads();

  // P = Q K^T  (m=t, n=u, k=feature)
  f32x4 p[4][4] = {};
#pragma unroll
  for (int k0 = 0; k0 < 4; ++k0) {
    bf16x8 av[4], bv[4];
#pragma unroll
    for (int mi = 0; mi < 4; ++mi) av[mi] = *(const bf16x8*)&R1[k0 * 4096 + (mW + mi * 16 + fr) * 32 + qd * 8];
#pragma unroll
    for (int ni = 0; ni < 4; ++ni) bv[ni] = *(const bf16x8*)&R2[k0 * 4096 + (nW + ni * 16 + fr) * 32 + qd * 8];
#pragma unroll
    for (int mi = 0; mi < 4; ++mi)
#pragma unroll
      for (int ni = 0; ni < 4; ++ni)
        p[mi][ni] = mf(av[mi], bv[ni], p[mi][ni]);
  }
  __syncthreads();   // all waves done reading Q,K from LDS

  // stage a 64-u half of a transposed matrix into a 16KB region (2 panels)
  auto stageHalf = [&](const u16* g, int h, u16* l) {
    const int pl = wave >> 1, r0v = (wave & 1) * 64;
    const u16* gp = g + cb + (size_t)(r0v + (lane >> 2)) * kM + h * 64 + pl * 32 + (lane & 3) * 8;
    u16* lp = l + pl * 4096 + r0v * 32;
#pragma unroll
    for (int i = 0; i < 4; ++i) gl_lds16(gp + (size_t)i * 16 * kM, lp + i * 512);
  };

  // async: half0 of Vt -> R2[0:8192), Kwt -> R2[8192:16384)
  stageHalf(VtG, 0, R2);
  stageHalf(KwtG, 0, R2 + 8192);

  // masked/decayed scores -> At in R1 (panels over u)
#pragma unroll
  for (int mi = 0; mi < 4; ++mi)
#pragma unroll
    for (int r = 0; r < 4; ++r) {
      const int tl = mW + mi * 16 + qd * 4 + r;
#pragma unroll
      for (int ni = 0; ni < 4; ++ni) {
        const int u = nW + ni * 16 + fr;
        float val = 0.f;
        if (u < tl) val = kLR * exp2f((float)(tl - 1 - u) * kLog2d) * p[mi][ni][r];
        R1[(u >> 5) * 4096 + tl * 32 + (u & 31)] = f2bf(val);
      }
    }
  __syncthreads();

  f32x4 o1[4][4] = {}, ua[4][4] = {};
#pragma unroll 1
  for (int h = 0; h < 2; ++h) {
    if (h == 1) {
      __syncthreads();
      stageHalf(VtG, 1, R2);
      stageHalf(KwtG, 1, R2 + 8192);
      __syncthreads();
    }
#pragma unroll
    for (int kl = 0; kl < 2; ++kl) {
      const int kg = h * 2 + kl;
      bf16x8 atf[4], vtf[4], kwf[4];
#pragma unroll
      for (int mi = 0; mi < 4; ++mi) atf[mi] = *(const bf16x8*)&R1[kg * 4096 + (mW + mi * 16 + fr) * 32 + qd * 8];
#pragma unroll
      for (int ni = 0; ni < 4; ++ni) vtf[ni] = *(const bf16x8*)&R2[kl * 4096 + (nW + ni * 16 + fr) * 32 + qd * 8];
#pragma unroll
      for (int mi = 0; mi < 4; ++mi) kwf[mi] = *(const bf16x8*)&R2[8192 + kl * 4096 + (mW + mi * 16 + fr) * 32 + qd * 8];
#pragma unroll
      for (int mi = 0; mi < 4; ++mi)
#pragma unroll
        for (int ni = 0; ni < 4; ++ni) {
          o1[mi][ni] = mf(atf[mi], vtf[ni], o1[mi][ni]);   // O1[t][i]
          ua[ni][mi] = mf(vtf[ni], kwf[mi], ua[ni][mi]);   // U[i][j]
        }
    }
  }

  float* O1g = O1 + cb;
  float* SUg = SU + cb;
#pragma unroll
  for (int mi = 0; mi < 4; ++mi)
#pragma unroll
    for (int ni = 0; ni < 4; ++ni)
#pragma unroll
      for (int r = 0; r < 4; ++r) {
        O1g[(size_t)(mW + mi * 16 + qd * 4 + r) * kM + nW + ni * 16 + fr] = o1[mi][ni][r];
        SUg[(size_t)(nW + ni * 16 + qd * 4 + r) * kM + mW + mi * 16 + fr] = ua[ni][mi][r];
      }
}

// ---------------------------------------------------------------------------
// inter-chunk scan: Sb16[c] = bf16(state before chunk c); carry -> state_out
// ---------------------------------------------------------------------------
__global__ __launch_bounds__(256)
void scan_kernel(const float* __restrict__ SU, u16* __restrict__ Sb16,
                 float* __restrict__ state_out)
{
  const int e  = blockIdx.x * 256 + threadIdx.x;
  const int b  = e >> 14;
  const int ij = e & 16383;
  const float* base = SU + (size_t)b * kNC * 16384 + ij;
  u16* sb = Sb16 + (size_t)b * kNC * 16384 + ij;
  const float dC = exp2f(128.0f * kLog2d);
  float prev = 0.f;
#pragma unroll
  for (int c2 = 0; c2 < kNC; ++c2) {
    const float u = base[(size_t)c2 * 16384];
    sb[(size_t)c2 * 16384] = f2bf(prev);
    prev = fmaf(dC, prev, u);
  }
  state_out[e] = prev;
}

// ---------------------------------------------------------------------------
// chunk_combine: O2 = Q S^T (MFMA); OutS = bf16(O1 + d^t * O2)
// ---------------------------------------------------------------------------
__global__ __launch_bounds__(256)
void chunk_combine_kernel(const u16* __restrict__ Qg, const u16* __restrict__ Sb16,
                          const float* __restrict__ O1, u16* __restrict__ OutS)
{
  __shared__ __align__(16) u16 R1[16384];
  __shared__ __align__(16) u16 R2[16384];
  const int c = blockIdx.x, b = blockIdx.y;
  const size_t cb = (size_t)(b * kNC + c) * 16384;
  const int tid = threadIdx.x, wave = tid >> 6, lane = tid & 63;
  const int fr = lane & 15, qd = lane >> 4;
  const int mW = (wave >> 1) * 64, nW = (wave & 1) * 64;
  {
    const size_t go = cb + (size_t)(lane >> 2) * kM + wave * 32 + (lane & 3) * 8;
    u16* l1 = R1 + wave * 4096;
    u16* l2 = R2 + wave * 4096;
#pragma unroll
    for (int i = 0; i < 8; ++i) {
      gl_lds16(Qg + go + (size_t)i * 16 * kM, l1 + i * 512);
      gl_lds16(Sb16 + go + (size_t)i * 16 * kM, l2 + i * 512);
    }
  }
  __syncthreads();
  f32x4 o2[4][4] = {};
#pragma unroll
  for (int k0 = 0; k0 < 4; ++k0) {
    bf16x8 av[4], bv[4];
#pragma unroll
    for (int mi = 0; mi < 4; ++mi) av[mi] = *(const bf16x8*)&R1[k0 * 4096 + (mW + mi * 16 + fr) * 32 + qd * 8];
#pragma unroll
    for (int ni = 0; ni < 4; ++ni) bv[ni] = *(const bf16x8*)&R2[k0 * 4096 + (nW + ni * 16 + fr) * 32 + qd * 8];
#pragma unroll
    for (int mi = 0; mi < 4; ++mi)
#pragma unroll
      for (int ni = 0; ni < 4; ++ni)
        o2[mi][ni] = mf(av[mi], bv[ni], o2[mi][ni]);
  }
  const float* O1g = O1 + cb;
  u16* Og = OutS + cb;
#pragma unroll
  for (int mi = 0; mi < 4; ++mi)
#pragma unroll
    for (int r = 0; r < 4; ++r) {
      const int tl = mW + mi * 16 + qd * 4 + r;
      const float dt = exp2f((float)tl * kLog2d);
#pragma unroll
      for (int ni = 0; ni < 4; ++ni) {
        const int ii = nW + ni * 16 + fr;
        Og[(size_t)tl * kM + ii] = f2bf(fmaf(dt, o2[mi][ni][r], O1g[(size_t)tl * kM + ii]));
      }
    }
}

// ---------------------------------------------------------------------------
extern "C" void kernel_launch(void* const* d_in, const int* in_sizes, int n_in,
                              void* d_out, int out_size, void* d_ws, size_t ws_size,
                              hipStream_t stream) {
  const float* x  = (const float*)d_in[0];
  const float* Wk = (const float*)d_in[1];
  const float* bk = (const float*)d_in[2];
  const float* Wv = (const float*)d_in[3];
  const float* bv = (const float*)d_in[4];
  const float* Wq = (const float*)d_in[5];
  const float* bq = (const float*)d_in[6];
  const float* Wo = (const float*)d_in[7];
  const float* bo = (const float*)d_in[8];

  char* w = (char*)d_ws;
  u16* xh = (u16*)w;                          w += (size_t)kRS * kD * 2;     // 33.5 MB
  u16* Wkvq = (u16*)w;                        w += (size_t)384 * kD * 2;
  u16* Woh = (u16*)w;                         w += (size_t)kD * kM * 2;
  u16* Kb16 = (u16*)w;                        w += (size_t)kRS * kM * 2;
  u16* Vb16 = (u16*)w;                        w += (size_t)kRS * kM * 2;
  u16* Qb16 = (u16*)w;                        w += (size_t)kRS * kM * 2;
  float* O1 = (float*)w;                      w += (size_t)kRS * kM * 4;
  float* SU = (float*)w;                      w += (size_t)kRS * kM * 4;
  u16* Sb16 = (u16*)w;                        w += (size_t)kRS * kM * 2;
  u16* OutS = (u16*)w;                        w += (size_t)kRS * kM * 2;
  // Kwt/Vt alias xh (xh is dead after gemm_proj; transpose runs after it)
  u16* Kwt = xh;
  u16* Vt  = xh + (size_t)kRS * kM;

  float* y = (float*)d_out;
  float* state_out = y + (size_t)kRS * kD;

  dim3 blk(256);
  cast_x_kernel<<<dim3(kRS * kD / 4 / 256), blk, 0, stream>>>(x, xh, kRS * kD);
  cast_w_kernel<<<dim3(524288 / 4 / 256), blk, 0, stream>>>(Wk, Wv, Wq, Wo, Wkvq, Woh);
  gemm_proj<<<dim3(kRS / 128, 3), blk, 0, stream>>>(xh, Wkvq, bk, bv, bq, Kb16, Vb16, Qb16);
  transpose_kv_kernel<<<dim3(kNC, kB, 2), blk, 0, stream>>>(Kb16, Vb16, Kwt, Vt);
  chunk_intra_kernel<<<dim3(kNC, kB), blk, 0, stream>>>(Qb16, Kb16, Vt, Kwt, O1, SU);
  scan_kernel<<<dim3(kB * kM * kM / 256), blk, 0, stream>>>(SU, Sb16, state_out);
  chunk_combine_kernel<<<dim3(kNC, kB), blk, 0, stream>>>(Qb16, Sb16, O1, OutS);
  gemm_final<<<dim3(kRS / 128, kD / 128), blk, 0, stream>>>(OutS, Woh, bo, y);
}

// Round 4
// 190.100 us; speedup vs baseline: 2.3999x; 1.1044x over previous
//
#include <hip/hip_runtime.h>
#include <math.h>

namespace {
constexpr int kB = 4;
constexpr int kS = 4096;
constexpr int kD = 1024;
constexpr int kM = 128;
constexpr int kC = 64;           // chunk length
constexpr int kNC = kS / kC;     // 64 chunks per batch
constexpr int kRS = kB * kS;     // 16384 rows
constexpr float kLR = 0.01f;
constexpr float kLog2d = -0.0144995696f;   // log2(0.99)
}

typedef __bf16 bf16x8 __attribute__((ext_vector_type(8)));
typedef float  f32x4  __attribute__((ext_vector_type(4)));
typedef unsigned short u16;
typedef unsigned int   u32;

__device__ __forceinline__ u16 f2bf(float f) {
  u32 x = __float_as_uint(f);
  u32 r = (x + 0x7fffu + ((x >> 16) & 1u)) >> 16;   // RNE
  return (u16)r;
}

__device__ __forceinline__ float bf2f(u16 h) {
  return __uint_as_float(((u32)h) << 16);
}

__device__ __forceinline__ void gl_lds16(const void* g, void* l) {
  __builtin_amdgcn_global_load_lds(
      (const __attribute__((address_space(1))) void*)g,
      (__attribute__((address_space(3))) void*)l, 16, 0, 0);
}

__device__ __forceinline__ f32x4 mf(bf16x8 a, bf16x8 b, f32x4 c) {
  return __builtin_amdgcn_mfma_f32_16x16x32_bf16(a, b, c, 0, 0, 0);
}

// ---------------------------------------------------------------------------
// cast Wk|Wv|Wq (concat -> Wkvq[384][1024]) and Wo -> Woh[1024][128], bf16
// ---------------------------------------------------------------------------
__global__ __launch_bounds__(256)
void cast_w_kernel(const float* __restrict__ Wk, const float* __restrict__ Wv,
                   const float* __restrict__ Wq, const float* __restrict__ Wo,
                   u16* __restrict__ Wkvq, u16* __restrict__ Woh)
{
  int i = (blockIdx.x * 256 + threadIdx.x) * 4;   // < 524288
  const float* src;
  u16* dst;
  if (i < 393216) {
    src = (i < 131072) ? Wk + i : (i < 262144) ? Wv + (i - 131072) : Wq + (i - 262144);
    dst = Wkvq + i;
  } else {
    src = Wo + (i - 393216);
    dst = Woh + (i - 393216);
  }
  float4 v = *(const float4*)src;
  ushort4 o;
  o.x = f2bf(v.x); o.y = f2bf(v.y); o.z = f2bf(v.z); o.w = f2bf(v.w);
  *(ushort4*)dst = o;
}

// ---------------------------------------------------------------------------
// Kernel A: fused projection + chunk-intra. One block per (chunk c, batch b),
// chunk = 64 rows. Grid 64x4 = 256 blocks (1/CU).
//   proj: [64 t][384 n] = x_chunk @ Wkvq^T + bias   (bf16 MFMA, fp32->bf16
//         cast of x done in staging; weights staged via global_load_lds)
//   distribute accs into LDS layouts: Qs/Ks (feat panels), Vt/Kwt (u panels,
//         Kwt pre-scaled by LR*d^{63-u}), Q also -> global (for kernel B)
//   P = Q K^T -> mask/decay -> At (u panels, overwrites Ks region)
//   O1 = At * V^T -> global bf16 [rows][128]
//   U  = V^T * Kw -> global fp32 per-chunk [128][128]
// LDS map (u16 idx): staging As[0..2047] Bs[2048..14335];
//   Qs[0..8191] Ks[8192..16383] Vt[16384..24575] Kwt[24576..32767]
//   At[8192..12287] (after P). Total 64 KB.
// ---------------------------------------------------------------------------
__global__ __launch_bounds__(256)
void fused_proj_intra(const float* __restrict__ x, const u16* __restrict__ Wkvq,
                      const float* __restrict__ bk, const float* __restrict__ bv,
                      const float* __restrict__ bq,
                      u16* __restrict__ Qg, u16* __restrict__ O1g,
                      float* __restrict__ SU)
{
  __shared__ __align__(16) u16 L[32768];   // 64 KB
  const int c = blockIdx.x, b = blockIdx.y;
  const int R0 = b * kS + c * kC;
  const int tid = threadIdx.x, w = tid >> 6, lane = tid & 63;
  const int fr = lane & 15, qd = lane >> 4;

  // ---------------- projection ----------------
  f32x4 acc[4][6] = {};
  const int xrow = tid >> 2, xcol = (tid & 3) * 8;
  const float* xp = x + (size_t)(R0 + xrow) * kD + xcol;
  u16* asDst = &L[xrow * 32 + xcol];
  const u16* wp = Wkvq + (size_t)(96 * w + (lane >> 2)) * kD + (lane & 3) * 8;
  u16* bsDst = &L[2048 + (96 * w) * 32];

  float4 xa = *(const float4*)xp;
  float4 xb = *(const float4*)(xp + 4);
  for (int k0 = 0; k0 < kD; k0 += 32) {
    __syncthreads();
#pragma unroll
    for (int i = 0; i < 6; ++i)
      gl_lds16(wp + k0 + (size_t)(i * 16) * kD, bsDst + i * 512);
    u16 xh8[8];
    xh8[0] = f2bf(xa.x); xh8[1] = f2bf(xa.y); xh8[2] = f2bf(xa.z); xh8[3] = f2bf(xa.w);
    xh8[4] = f2bf(xb.x); xh8[5] = f2bf(xb.y); xh8[6] = f2bf(xb.z); xh8[7] = f2bf(xb.w);
    *(uint4*)asDst = *(uint4*)xh8;
    __syncthreads();
    if (k0 + 32 < kD) {
      xa = *(const float4*)(xp + k0 + 32);
      xb = *(const float4*)(xp + k0 + 36);
    }
    bf16x8 av[4], bvv[6];
#pragma unroll
    for (int mi = 0; mi < 4; ++mi)
      av[mi] = *(const bf16x8*)&L[(mi * 16 + fr) * 32 + qd * 8];
#pragma unroll
    for (int nj = 0; nj < 6; ++nj)
      bvv[nj] = *(const bf16x8*)&L[2048 + (96 * w + nj * 16 + fr) * 32 + qd * 8];
#pragma unroll
    for (int mi = 0; mi < 4; ++mi)
#pragma unroll
      for (int nj = 0; nj < 6; ++nj)
        acc[mi][nj] = mf(av[mi], bvv[nj], acc[mi][nj]);
  }
  __syncthreads();   // staging regions now dead; safe to build chunk layouts

  // ---------------- distribute K/V/Q into chunk layouts ----------------
  float dp63[16];    // LR * d^{63-t} for t = mi*16 + qd*4 + r
#pragma unroll
  for (int mi = 0; mi < 4; ++mi)
#pragma unroll
    for (int r = 0; r < 4; ++r)
      dp63[mi * 4 + r] = kLR * exp2f((float)(63 - (mi * 16 + qd * 4 + r)) * kLog2d);

#pragma unroll
  for (int nj = 0; nj < 6; ++nj) {
    const int n = 96 * w + nj * 16 + fr;
    const int slab = n >> 7, j = n & 127;
    const float* bp = (slab == 0) ? bk : (slab == 1) ? bv : bq;
    const float bias = bp[j];
#pragma unroll
    for (int mi = 0; mi < 4; ++mi)
#pragma unroll
      for (int r = 0; r < 4; ++r) {
        const int t = mi * 16 + qd * 4 + r;
        const float val = acc[mi][nj][r] + bias;
        const u16 h = f2bf(val);
        if (slab == 0) {
          L[8192 + (j >> 5) * 2048 + t * 32 + (j & 31)] = h;                       // Ks
          L[24576 + (t >> 5) * 4096 + j * 32 + (t & 31)] = f2bf(val * dp63[mi * 4 + r]); // Kwt
        } else if (slab == 1) {
          L[16384 + (t >> 5) * 4096 + j * 32 + (t & 31)] = h;                      // Vt
        } else {
          L[(j >> 5) * 2048 + t * 32 + (j & 31)] = h;                              // Qs
          Qg[(size_t)(R0 + t) * kM + j] = h;
        }
      }
  }
  __syncthreads();

  // ---------------- P = Q K^T (64x64, wave quadrant 32x32) ----------------
  const int mP = (w >> 1) * 32, nP = (w & 1) * 32;
  f32x4 p[2][2] = {};
#pragma unroll
  for (int kp = 0; kp < 4; ++kp) {
    bf16x8 a2[2], b2[2];
#pragma unroll
    for (int mi = 0; mi < 2; ++mi)
      a2[mi] = *(const bf16x8*)&L[kp * 2048 + (mP + mi * 16 + fr) * 32 + qd * 8];
#pragma unroll
    for (int ni = 0; ni < 2; ++ni)
      b2[ni] = *(const bf16x8*)&L[8192 + kp * 2048 + (nP + ni * 16 + fr) * 32 + qd * 8];
#pragma unroll
    for (int mi = 0; mi < 2; ++mi)
#pragma unroll
      for (int ni = 0; ni < 2; ++ni)
        p[mi][ni] = mf(a2[mi], b2[ni], p[mi][ni]);
  }
  __syncthreads();   // Ks reads done; reuse its region for At

  // ---------------- mask + decay -> At (u panels) ----------------
#pragma unroll
  for (int mi = 0; mi < 2; ++mi)
#pragma unroll
    for (int r = 0; r < 4; ++r) {
      const int t = mP + mi * 16 + qd * 4 + r;
#pragma unroll
      for (int ni = 0; ni < 2; ++ni) {
        const int u = nP + ni * 16 + fr;
        float av2 = 0.f;
        if (u < t) av2 = kLR * exp2f((float)(t - 1 - u) * kLog2d) * p[mi][ni][r];
        L[8192 + (u >> 5) * 2048 + t * 32 + (u & 31)] = f2bf(av2);
      }
    }
  __syncthreads();

  // ---------------- O1 = At V^T, U = V^T Kw ----------------
  const int mO = (w >> 1) * 32, nO = (w & 1) * 64;   // O1: t-half x i-half
  const int mU = (w >> 1) * 64, nU = (w & 1) * 64;   // U: i-quad x j-quad
  f32x4 o1[2][4] = {}, uu[4][4] = {};
#pragma unroll
  for (int kp = 0; kp < 2; ++kp) {
    bf16x8 af[2], vb[4], va[4], ub[4];
#pragma unroll
    for (int mi = 0; mi < 2; ++mi)
      af[mi] = *(const bf16x8*)&L[8192 + kp * 2048 + (mO + mi * 16 + fr) * 32 + qd * 8];
#pragma unroll
    for (int ni = 0; ni < 4; ++ni)
      vb[ni] = *(const bf16x8*)&L[16384 + kp * 4096 + (nO + ni * 16 + fr) * 32 + qd * 8];
#pragma unroll
    for (int mi = 0; mi < 4; ++mi)
      va[mi] = *(const bf16x8*)&L[16384 + kp * 4096 + (mU + mi * 16 + fr) * 32 + qd * 8];
#pragma unroll
    for (int ni = 0; ni < 4; ++ni)
      ub[ni] = *(const bf16x8*)&L[24576 + kp * 4096 + (nU + ni * 16 + fr) * 32 + qd * 8];
#pragma unroll
    for (int mi = 0; mi < 2; ++mi)
#pragma unroll
      for (int ni = 0; ni < 4; ++ni)
        o1[mi][ni] = mf(af[mi], vb[ni], o1[mi][ni]);
#pragma unroll
    for (int mi = 0; mi < 4; ++mi)
#pragma unroll
      for (int ni = 0; ni < 4; ++ni)
        uu[mi][ni] = mf(va[mi], ub[ni], uu[mi][ni]);
  }

  // ---------------- epilogue stores ----------------
#pragma unroll
  for (int mi = 0; mi < 2; ++mi)
#pragma unroll
    for (int ni = 0; ni < 4; ++ni)
#pragma unroll
      for (int r = 0; r < 4; ++r) {
        const int t = mO + mi * 16 + qd * 4 + r, i = nO + ni * 16 + fr;
        O1g[(size_t)(R0 + t) * kM + i] = f2bf(o1[mi][ni][r]);
      }
  float* SUc = SU + (size_t)(b * kNC + c) * (kM * kM);
#pragma unroll
  for (int mi = 0; mi < 4; ++mi)
#pragma unroll
    for (int ni = 0; ni < 4; ++ni)
#pragma unroll
      for (int r = 0; r < 4; ++r) {
        const int i = mU + mi * 16 + qd * 4 + r, j = nU + ni * 16 + fr;
        SUc[i * kM + j] = uu[mi][ni][r];
      }
}

// ---------------------------------------------------------------------------
// inter-chunk scan: Sb16[c] = bf16(state before chunk c); carry -> state_out
// ---------------------------------------------------------------------------
__global__ __launch_bounds__(256)
void scan_kernel(const float* __restrict__ SU, u16* __restrict__ Sb16,
                 float* __restrict__ state_out)
{
  const int e = blockIdx.x * 256 + threadIdx.x;   // < kB * 16384
  const int b = e >> 14, ij = e & 16383;
  const float* base = SU + (size_t)b * kNC * 16384 + ij;
  u16* sb = Sb16 + (size_t)b * kNC * 16384 + ij;
  const float dC = exp2f((float)kC * kLog2d);
  float prev = 0.f;
#pragma unroll 8
  for (int c2 = 0; c2 < kNC; ++c2) {
    const float u = base[(size_t)c2 * 16384];
    sb[(size_t)c2 * 16384] = f2bf(prev);
    prev = fmaf(dC, prev, u);
  }
  state_out[e] = prev;
}

// ---------------------------------------------------------------------------
// Kernel B: fused combine + output GEMM. One block per (chunk, batch).
//   O2 = Q S^T (MFMA) ; Out = bf16(O1 + d^t O2) -> LDS A-panels
//   y  = Out @ Woh^T + bo   (B-fragments read directly from global; Woh L2-hot)
// LDS: Qs[0..8191] (4 panels 64x32), Ss[8192..24575] (4 panels 128x32),
//      OutP reuses Qs region. 48 KB.
// ---------------------------------------------------------------------------
__global__ __launch_bounds__(256)
void fused_combine_out(const u16* __restrict__ Qg, const u16* __restrict__ Sb16,
                       const u16* __restrict__ O1g, const u16* __restrict__ Woh,
                       const float* __restrict__ bo, float* __restrict__ y)
{
  __shared__ __align__(16) u16 L[24576];
  const int c = blockIdx.x, b = blockIdx.y;
  const int R0 = b * kS + c * kC;
  const int tid = threadIdx.x, w = tid >> 6, lane = tid & 63;
  const int fr = lane & 15, qd = lane >> 4;
  const size_t cbS = (size_t)(b * kNC + c) * 16384;

  // stage Qs (wave w = feat panel w) and Ss (wave w = j panel w)
  {
    const u16* gq = Qg + (size_t)(R0 + (lane >> 2)) * kM + w * 32 + (lane & 3) * 8;
    u16* lq = &L[w * 2048];
#pragma unroll
    for (int g = 0; g < 4; ++g)
      gl_lds16(gq + (size_t)(g * 16) * kM, lq + g * 512);
    const u16* gs = Sb16 + cbS + (size_t)(lane >> 2) * kM + w * 32 + (lane & 3) * 8;
    u16* ls = &L[8192 + w * 4096];
#pragma unroll
    for (int g = 0; g < 8; ++g)
      gl_lds16(gs + (size_t)(g * 16) * kM, ls + g * 512);
  }

  const int mO = (w >> 1) * 32, nO = (w & 1) * 64;
  // prefetch O1 (D-layout positions), overlaps staging
  u16 o1h[2][4][4];
#pragma unroll
  for (int mi = 0; mi < 2; ++mi)
#pragma unroll
    for (int ni = 0; ni < 4; ++ni)
#pragma unroll
      for (int r = 0; r < 4; ++r)
        o1h[mi][ni][r] =
            O1g[(size_t)(R0 + mO + mi * 16 + qd * 4 + r) * kM + nO + ni * 16 + fr];
  __syncthreads();

  // O2 = Q S^T
  f32x4 o2[2][4] = {};
#pragma unroll
  for (int kp = 0; kp < 4; ++kp) {
    bf16x8 aq[2], bs[4];
#pragma unroll
    for (int mi = 0; mi < 2; ++mi)
      aq[mi] = *(const bf16x8*)&L[kp * 2048 + (mO + mi * 16 + fr) * 32 + qd * 8];
#pragma unroll
    for (int ni = 0; ni < 4; ++ni)
      bs[ni] = *(const bf16x8*)&L[8192 + kp * 4096 + (nO + ni * 16 + fr) * 32 + qd * 8];
#pragma unroll
    for (int mi = 0; mi < 2; ++mi)
#pragma unroll
      for (int ni = 0; ni < 4; ++ni)
        o2[mi][ni] = mf(aq[mi], bs[ni], o2[mi][ni]);
  }
  __syncthreads();   // Qs reads done; reuse region for Out panels

  // Out = bf16(O1 + d^t * O2) -> feat panels over i
#pragma unroll
  for (int mi = 0; mi < 2; ++mi)
#pragma unroll
    for (int r = 0; r < 4; ++r) {
      const int t = mO + mi * 16 + qd * 4 + r;
      const float dt = exp2f((float)t * kLog2d);
#pragma unroll
      for (int ni = 0; ni < 4; ++ni) {
        const int i = nO + ni * 16 + fr;
        const float ov = fmaf(dt, o2[mi][ni][r], bf2f(o1h[mi][ni][r]));
        L[(i >> 5) * 2048 + t * 32 + (i & 31)] = f2bf(ov);
      }
    }
  __syncthreads();

  // y[t][d] = Out @ Woh^T + bo; wave covers d in [256w, 256w+256), 2 halves
#pragma unroll 1
  for (int h = 0; h < 2; ++h) {
    const int n0 = w * 256 + h * 128;
    f32x4 fy[4][8] = {};
#pragma unroll
    for (int kp = 0; kp < 4; ++kp) {
      bf16x8 ao[4], bw[8];
#pragma unroll
      for (int mi = 0; mi < 4; ++mi)
        ao[mi] = *(const bf16x8*)&L[kp * 2048 + (mi * 16 + fr) * 32 + qd * 8];
#pragma unroll
      for (int nj = 0; nj < 8; ++nj)
        bw[nj] = *(const bf16x8*)&Woh[(size_t)(n0 + nj * 16 + fr) * kM + kp * 32 + qd * 8];
#pragma unroll
      for (int mi = 0; mi < 4; ++mi)
#pragma unroll
        for (int nj = 0; nj < 8; ++nj)
          fy[mi][nj] = mf(ao[mi], bw[nj], fy[mi][nj]);
    }
#pragma unroll
    for (int nj = 0; nj < 8; ++nj) {
      const int d = n0 + nj * 16 + fr;
      const float bb = bo[d];
#pragma unroll
      for (int mi = 0; mi < 4; ++mi)
#pragma unroll
        for (int r = 0; r < 4; ++r)
          y[(size_t)(R0 + mi * 16 + qd * 4 + r) * kD + d] = fy[mi][nj][r] + bb;
    }
  }
}

// ---------------------------------------------------------------------------
extern "C" void kernel_launch(void* const* d_in, const int* in_sizes, int n_in,
                              void* d_out, int out_size, void* d_ws, size_t ws_size,
                              hipStream_t stream) {
  const float* x  = (const float*)d_in[0];
  const float* Wk = (const float*)d_in[1];
  const float* bk = (const float*)d_in[2];
  const float* Wv = (const float*)d_in[3];
  const float* bv = (const float*)d_in[4];
  const float* Wq = (const float*)d_in[5];
  const float* bq = (const float*)d_in[6];
  const float* Wo = (const float*)d_in[7];
  const float* bo = (const float*)d_in[8];

  char* wsp = (char*)d_ws;
  u16* Wkvq = (u16*)wsp;   wsp += (size_t)384 * 1024 * 2;
  u16* Woh  = (u16*)wsp;   wsp += (size_t)1024 * 128 * 2;
  u16* Qg   = (u16*)wsp;   wsp += (size_t)kRS * kM * 2;
  u16* O1g  = (u16*)wsp;   wsp += (size_t)kRS * kM * 2;
  float* SU = (float*)wsp; wsp += (size_t)kB * kNC * 16384 * 4;
  u16* Sb16 = (u16*)wsp;   wsp += (size_t)kB * kNC * 16384 * 2;

  float* y = (float*)d_out;
  float* state_out = y + (size_t)kRS * kD;

  dim3 blk(256);
  cast_w_kernel<<<dim3(512), blk, 0, stream>>>(Wk, Wv, Wq, Wo, Wkvq, Woh);
  fused_proj_intra<<<dim3(kNC, kB), blk, 0, stream>>>(x, Wkvq, bk, bv, bq, Qg, O1g, SU);
  scan_kernel<<<dim3(kB * 16384 / 256), blk, 0, stream>>>(SU, Sb16, state_out);
  fused_combine_out<<<dim3(kNC, kB), blk, 0, stream>>>(Qg, Sb16, O1g, Woh, bo, y);
}